// Round 5
// baseline (51.778 us; speedup 1.0000x reference)
//
#include <hip/hip_runtime.h>
#include <stdint.h>

#define N_GATES    16384
#define NUM_IN     256
#define NUM_OUT    256
#define MID_LAYERS 15
#define LAYERS_TOT 16              // layer0 + 15 mid (out layer handled separately)
#define W          4096
#define BLOCK      1024
#define WG_COLS    16              // bit-columns per workgroup (uint16 words)
#define NUM_WG     (W / WG_COLS)   // 256 -> one WG per CU
#define QPT        4               // quads (of 4 gates) per thread

// ---------------------------------------------------------------------------
// Prep: greedy two-choice operand orientation.
// NAND/NOR are commutative, so each gate may swap (a,b). The two operand
// reads of gate-slot k land in two distinct wave instructions; greedily
// orienting each gate to the less-loaded LDS bank drives per-instruction
// max bank load from ~4.8 (random) toward ~2, and 2-way is conflict-free.
// Emits one u32 descriptor per gate: a*2 | nor<<15 | (b*2)<<16 (pre-scaled
// byte addresses into the u16 layer buffer). No index remap needed: outputs
// stay at original gate positions.
// Grid: 256 blocks = (layer 0..15, wave 0..15), 64 threads each.
// ---------------------------------------------------------------------------
__global__ __launch_bounds__(64)
void prep_sched(const int2* __restrict__ idx0,    // 16384 pairs, [0,256)
                const int*  __restrict__ nor0,    // 16384
                const int2* __restrict__ idx_mid, // 15*16384 pairs, [0,16384)
                const int*  __restrict__ nor_mid, // 15*16384
                uint32_t*   __restrict__ ws)      // 16*16384 descriptors
{
    __shared__ uint32_t desc_s[1024];
    __shared__ uint32_t binsA[32 * 16];
    __shared__ uint32_t binsB[32 * 16];

    const int l = blockIdx.x >> 4;   // layer 0..15
    const int w = blockIdx.x & 15;   // wave group 0..15
    const int t = threadIdx.x;       // 0..63

    const int2* idx = (l == 0) ? idx0 : idx_mid + (size_t)(l - 1) * N_GATES;
    const int*  nor = (l == 0) ? nor0 : nor_mid + (size_t)(l - 1) * N_GATES;

    // phase 1: stage this (layer,wave)'s 1024 gate descs into LDS.
    // wave w's gates: g = w*256 + q*4096 + i  (q 0..3, i 0..255), i = lane*4+k
    for (int j = t; j < 1024; j += 64) {
        int q = j >> 8, i = j & 255;
        int g = w * 256 + q * 4096 + i;
        int2 ab = idx[g];
        int  nn = nor[g];
        desc_s[j] = (uint32_t)ab.x | ((uint32_t)ab.y << 14) | ((uint32_t)nn << 28);
    }
    for (int j = t; j < 32 * 16; j += 64) { binsA[j] = 0; binsB[j] = 0; }
    __syncthreads();

    if (t < 16) {
        const int q = t >> 2, k = t & 3;
        for (int lane = 0; lane < 64; ++lane) {
            uint32_t d = desc_s[q * 256 + lane * 4 + k];
            uint32_t a = d & 0x3FFFu, b = (d >> 14) & 0x3FFFu, n = d >> 28;
            uint32_t ba = (a >> 1) & 31, bb = (b >> 1) & 31;
            uint32_t laa = binsA[ba * 16 + t], lbb = binsB[bb * 16 + t];
            uint32_t lab = binsA[bb * 16 + t], lba = binsB[ba * 16 + t];
            uint32_t c0 = laa > lbb ? laa : lbb;   // keep order
            uint32_t c1 = lab > lba ? lab : lba;   // swapped
            uint32_t s0 = a, s1 = b, nA = laa, nB = lbb;
            if (c1 < c0) { s0 = b; s1 = a; nA = lab; nB = lba; }
            binsA[((s0 >> 1) & 31) * 16 + t] = nA + 1;
            binsB[((s1 >> 1) & 31) * 16 + t] = nB + 1;
            uint32_t Q = (uint32_t)(w * 64 + lane + q * 1024);
            ws[(size_t)l * N_GATES + Q * 4 + k] = (s0 << 1) | (n << 15) | (s1 << 17);
        }
    }
}

// ---------------------------------------------------------------------------
// Main kernel (scheduled descriptors). One WG owns 16 bit-columns (u16
// words); full layer slice 32KB, double-buffered; 17 layers in-workgroup.
// ---------------------------------------------------------------------------
__global__ __launch_bounds__(BLOCK, 2)
void nand_graph_sched(const uint32_t* __restrict__ input_bits, // 256*4096 int 0/1
                      const uint32_t* __restrict__ ws_desc,    // 16*16384 packed descs
                      const int2*     __restrict__ idx_out,    // 256 pairs
                      const uint32_t* __restrict__ nor_out,    // 256 flags
                      int*            __restrict__ out)        // 256*4096 int 0/1
{
    extern __shared__ __align__(16) uint16_t lds16[];
    uint16_t* bufA = lds16;
    uint16_t* bufB = lds16 + N_GATES;
    uint16_t* wrd  = lds16 + 2 * N_GATES;   // 256 u16

    const int tid     = threadIdx.x;
    const int lane    = tid & 63;
    const int wave    = tid >> 6;
    const int colbase = blockIdx.x * WG_COLS;
    const uint4* dsc4 = reinterpret_cast<const uint4*>(ws_desc); // [l*4096 + q*1024 + tid]

    uint4 dsc[QPT];
    #pragma unroll
    for (int q = 0; q < QPT; ++q)            // layer-0 descriptors
        dsc[q] = dsc4[q * 1024 + tid];

    // ---- pack input_bits columns [colbase, colbase+16) into wrd[256] ----
    #pragma unroll
    for (int it = wave; it < NUM_IN / 4; it += BLOCK / 64) {
        int r = it * 4 + (lane >> 4);
        int c = lane & 15;
        uint32_t v = input_bits[r * W + colbase + c];
        unsigned long long m = __ballot(v != 0u);
        if ((lane & 15) == 0)
            wrd[r] = (uint16_t)(m >> ((lane >> 4) * 16));
    }
    __syncthreads();

    auto gate = [](const uint16_t* __restrict__ src, uint32_t d) -> uint32_t {
        uint32_t a2 = d & 0x7FFEu;
        uint32_t b2 = d >> 16;
        uint32_t va = *(const uint16_t*)((const char*)src + a2);
        uint32_t vb = *(const uint16_t*)((const char*)src + b2);
        return ~((d & 0x8000u) ? (va | vb) : (va & vb));
    };

    auto run_gates = [&](const uint16_t* __restrict__ src, uint16_t* __restrict__ dst) {
        #pragma unroll
        for (int q = 0; q < QPT; ++q) {
            int Q = tid + q * BLOCK;
            uint32_t r0 = gate(src, dsc[q].x);
            uint32_t r1 = gate(src, dsc[q].y);
            uint32_t r2 = gate(src, dsc[q].z);
            uint32_t r3 = gate(src, dsc[q].w);
            uint32_t lo = (r0 & 0xFFFFu) | (r1 << 16);
            uint32_t hi = (r2 & 0xFFFFu) | (r3 << 16);
            *reinterpret_cast<uint2*>(dst + 4 * Q) = make_uint2(lo, hi); // ds_write_b64, conflict-free
        }
    };

    // ---- layer 0 (reads wrd) ----
    run_gates(wrd, bufA);
    #pragma unroll
    for (int q = 0; q < QPT; ++q)            // prefetch mid-layer 0 descs
        dsc[q] = dsc4[1 * 4096 + q * 1024 + tid];
    __syncthreads();

    // ---- 15 mid layers, ping-pong, descriptor prefetch across barrier ----
    uint16_t* cur = bufA;
    uint16_t* nxt = bufB;
    for (int l = 1; l <= MID_LAYERS; ++l) {
        run_gates(cur, nxt);
        if (l + 1 <= MID_LAYERS) {
            #pragma unroll
            for (int q = 0; q < QPT; ++q)
                dsc[q] = dsc4[(l + 1) * 4096 + q * 1024 + tid];
        }
        __syncthreads();
        uint16_t* tp = cur; cur = nxt; nxt = tp;
    }

    // ---- output layer: 256 gates -> wrd ----
    if (tid < NUM_OUT) {
        int2 ix = idx_out[tid];
        uint32_t a = cur[ix.x];
        uint32_t b = cur[ix.y];
        wrd[tid] = (uint16_t)~(nor_out[tid] ? (a | b) : (a & b));
    }
    __syncthreads();

    // ---- unpack: 256 rows x 16 cols of int 0/1 ----
    for (int i = tid; i < NUM_OUT * WG_COLS; i += BLOCK) {
        int r = i >> 4, c = i & 15;
        out[r * W + colbase + c] = (int)((wrd[r] >> c) & 1u);
    }
}

// ---------------------------------------------------------------------------
// Fallback (R4 kernel, unscheduled) — used only if ws_size < 1MB.
// ---------------------------------------------------------------------------
__global__ __launch_bounds__(BLOCK, 2)
void nand_graph_kernel(const uint32_t* __restrict__ input_bits,
                       const int4*     __restrict__ idx0_4,
                       const int4*     __restrict__ idx_mid_4,
                       const int2*     __restrict__ idx_out,
                       const int4*     __restrict__ nor0_4,
                       const int4*     __restrict__ nor_mid_4,
                       const uint32_t* __restrict__ nor_out,
                       int*            __restrict__ out)
{
    extern __shared__ __align__(16) uint16_t lds16[];
    uint16_t* bufA = lds16;
    uint16_t* bufB = lds16 + N_GATES;
    uint16_t* wrd  = lds16 + 2 * N_GATES;

    const int tid     = threadIdx.x;
    const int lane    = tid & 63;
    const int wave    = tid >> 6;
    const int colbase = blockIdx.x * WG_COLS;

    int4 ixA[QPT], ixB[QPT], nnq[QPT];
    #pragma unroll
    for (int q = 0; q < QPT; ++q) {
        int Q = tid + q * BLOCK;
        ixA[q] = idx0_4[2 * Q];
        ixB[q] = idx0_4[2 * Q + 1];
        nnq[q] = nor0_4[Q];
    }
    #pragma unroll
    for (int it = wave; it < NUM_IN / 4; it += BLOCK / 64) {
        int r = it * 4 + (lane >> 4);
        int c = lane & 15;
        uint32_t v = input_bits[r * W + colbase + c];
        unsigned long long m = __ballot(v != 0u);
        if ((lane & 15) == 0)
            wrd[r] = (uint16_t)(m >> ((lane >> 4) * 16));
    }
    __syncthreads();

    auto run_gates = [&](const uint16_t* __restrict__ src, uint16_t* __restrict__ dst) {
        #pragma unroll
        for (int q = 0; q < QPT; ++q) {
            int Q = tid + q * BLOCK;
            uint32_t a0 = src[ixA[q].x], b0 = src[ixA[q].y];
            uint32_t a1 = src[ixA[q].z], b1 = src[ixA[q].w];
            uint32_t a2 = src[ixB[q].x], b2 = src[ixB[q].y];
            uint32_t a3 = src[ixB[q].z], b3 = src[ixB[q].w];
            uint32_t r0 = ~(nnq[q].x ? (a0 | b0) : (a0 & b0));
            uint32_t r1 = ~(nnq[q].y ? (a1 | b1) : (a1 & b1));
            uint32_t r2 = ~(nnq[q].z ? (a2 | b2) : (a2 & b2));
            uint32_t r3 = ~(nnq[q].w ? (a3 | b3) : (a3 & b3));
            uint32_t lo = (r0 & 0xFFFFu) | (r1 << 16);
            uint32_t hi = (r2 & 0xFFFFu) | (r3 << 16);
            *reinterpret_cast<uint2*>(dst + 4 * Q) = make_uint2(lo, hi);
        }
    };

    run_gates(wrd, bufA);
    {
        #pragma unroll
        for (int q = 0; q < QPT; ++q) {
            int Q = tid + q * BLOCK;
            ixA[q] = idx_mid_4[2 * Q];
            ixB[q] = idx_mid_4[2 * Q + 1];
            nnq[q] = nor_mid_4[Q];
        }
    }
    __syncthreads();

    uint16_t* cur = bufA;
    uint16_t* nxt = bufB;
    for (int l = 0; l < MID_LAYERS; ++l) {
        run_gates(cur, nxt);
        if (l + 1 < MID_LAYERS) {
            const int4* i4 = idx_mid_4 + (size_t)(l + 1) * (N_GATES / 2);
            const int4* n4 = nor_mid_4 + (size_t)(l + 1) * (N_GATES / 4);
            #pragma unroll
            for (int q = 0; q < QPT; ++q) {
                int Q = tid + q * BLOCK;
                ixA[q] = i4[2 * Q];
                ixB[q] = i4[2 * Q + 1];
                nnq[q] = n4[Q];
            }
        }
        __syncthreads();
        uint16_t* tp = cur; cur = nxt; nxt = tp;
    }

    if (tid < NUM_OUT) {
        int2 ix = idx_out[tid];
        uint32_t a = cur[ix.x];
        uint32_t b = cur[ix.y];
        wrd[tid] = (uint16_t)~(nor_out[tid] ? (a | b) : (a & b));
    }
    __syncthreads();
    for (int i = tid; i < NUM_OUT * WG_COLS; i += BLOCK) {
        int r = i >> 4, c = i & 15;
        out[r * W + colbase + c] = (int)((wrd[r] >> c) & 1u);
    }
}

extern "C" void kernel_launch(void* const* d_in, const int* in_sizes, int n_in,
                              void* d_out, int out_size, void* d_ws, size_t ws_size,
                              hipStream_t stream) {
    const uint32_t* input_bits = (const uint32_t*)d_in[0];
    const int2*     idx0       = (const int2*)d_in[1];
    const int2*     idx_mid    = (const int2*)d_in[2];
    const int2*     idx_out    = (const int2*)d_in[3];
    const int*      nor0       = (const int*)d_in[4];
    const int*      nor_mid    = (const int*)d_in[5];
    const uint32_t* nor_out    = (const uint32_t*)d_in[6];
    int*            out        = (int*)d_out;

    const size_t lds_bytes = (size_t)(2 * N_GATES + 256) * sizeof(uint16_t); // 66048 B
    const size_t desc_bytes = (size_t)LAYERS_TOT * N_GATES * sizeof(uint32_t); // 1 MB

    if (ws_size >= desc_bytes) {
        uint32_t* ws = (uint32_t*)d_ws;
        prep_sched<<<dim3(256), dim3(64), 0, stream>>>(idx0, nor0, idx_mid, nor_mid, ws);
        hipFuncSetAttribute(reinterpret_cast<const void*>(nand_graph_sched),
                            hipFuncAttributeMaxDynamicSharedMemorySize, (int)lds_bytes);
        nand_graph_sched<<<dim3(NUM_WG), dim3(BLOCK), lds_bytes, stream>>>(
            input_bits, ws, idx_out, nor_out, out);
    } else {
        hipFuncSetAttribute(reinterpret_cast<const void*>(nand_graph_kernel),
                            hipFuncAttributeMaxDynamicSharedMemorySize, (int)lds_bytes);
        nand_graph_kernel<<<dim3(NUM_WG), dim3(BLOCK), lds_bytes, stream>>>(
            input_bits, (const int4*)idx0, (const int4*)idx_mid, idx_out,
            (const int4*)nor0, (const int4*)nor_mid, nor_out, out);
    }
}